// Round 1
// baseline (1119.144 us; speedup 1.0000x reference)
//
#include <hip/hip_runtime.h>
#include <hip/hip_bf16.h>

// FusedMoEWithLoRA: grouped bf16-MFMA GEMM formulation.
// Routing -> padded per-expert row blocks; LoRA rank-16 deltas folded into the
// GEMM K dimension (K += L*R = 64) with per-token adapter masking applied to
// the expanded u/v strips.

#define E_   8
#define H_   2048
#define I_   1024
#define I2_  2048
#define K_   2
#define L_   4
#define R_   16
#define T_   4096
#define LR_  64            // L_*R_
#define BM   128
#define BN   128
#define BK   32
#define MAXPAD 9216        // 8192 + 8*128 worst-case padded rows
#define KTOT1 (H_ + LR_)   // 2112
#define KTOT2 (I_ + LR_)   // 1088

typedef __attribute__((ext_vector_type(8))) __bf16 bf16x8;
typedef __attribute__((ext_vector_type(4))) float  f32x4;

__device__ __forceinline__ unsigned short f2bf(float f) {
  union { float f; unsigned u; } v; v.f = f;
  unsigned u = v.u;
  u += 0x7fffu + ((u >> 16) & 1u);   // RNE
  return (unsigned short)(u >> 16);
}
__device__ __forceinline__ float bf2f(unsigned short s) {
  union { unsigned u; float f; } v; v.u = ((unsigned)s) << 16;
  return v.f;
}
__device__ __forceinline__ unsigned pack2(float a, float b) {
  __hip_bfloat162 h = __float22bfloat162_rn(float2{a, b});
  union { __hip_bfloat162 h; unsigned u; } v; v.h = h;
  return v.u;
}

// ---------------- routing ----------------
__global__ void k_count(const int* __restrict__ topk_ids, int* __restrict__ cnt) {
  int i = blockIdx.x * blockDim.x + threadIdx.x;
  if (i < T_ * K_) atomicAdd(&cnt[topk_ids[i]], 1);
}

__global__ void k_prefix(const int* __restrict__ cnt, int* __restrict__ pad_off) {
  if (threadIdx.x == 0) {
    int off = 0;
    for (int e = 0; e < E_; ++e) {
      pad_off[e] = off;
      off += ((cnt[e] + BM - 1) / BM) * BM;
    }
    pad_off[E_] = off;
  }
}

__global__ void k_scatter(const int* __restrict__ topk_ids, const float* __restrict__ topk_w,
                          const int* __restrict__ tli, const int* __restrict__ pad_off,
                          int* __restrict__ cnt2, int* __restrict__ tok,
                          float* __restrict__ wgt, int* __restrict__ lidx) {
  int i = blockIdx.x * blockDim.x + threadIdx.x;
  if (i < T_ * K_) {
    int e = topk_ids[i];
    int pos = atomicAdd(&cnt2[e], 1);
    int g = pad_off[e] + pos;
    int t = i / K_;
    tok[g] = t;
    wgt[g] = topk_w[i];
    lidx[g] = tli[t];
  }
}

// ---------------- LoRA u = hidden . gu_a  (expanded/masked to 64-wide strip) ----------------
__global__ void k_lora_u(const float* __restrict__ hidden, const float* __restrict__ gua,
                         const int* __restrict__ tok, const int* __restrict__ lidx,
                         const int* __restrict__ pad_off, const int* __restrict__ cnt,
                         unsigned short* __restrict__ u_exp) {
  const int lane = threadIdx.x & 63;
  const int wid  = threadIdx.x >> 6;
  const int g = blockIdx.x * 4 + wid;
  int e = -1;
#pragma unroll
  for (int i = 0; i < E_; ++i)
    if (g >= pad_off[i] && g < pad_off[i + 1]) e = i;
  const bool valid = (e >= 0) && ((g - pad_off[e]) < cnt[e]);
  float sum[R_];
#pragma unroll
  for (int r = 0; r < R_; ++r) sum[r] = 0.f;
  int l = 0;
  if (valid) {
    const int t = tok[g];
    l = lidx[g];
    const float* hp = hidden + (size_t)t * H_;
    const float* ap = gua + ((size_t)l * E_ + e) * R_ * H_;
    for (int k = lane; k < H_; k += 64) {
      const float hv = hp[k];
#pragma unroll
      for (int r = 0; r < R_; ++r) sum[r] += hv * ap[(size_t)r * H_ + k];
    }
#pragma unroll
    for (int r = 0; r < R_; ++r)
#pragma unroll
      for (int off = 32; off > 0; off >>= 1) sum[r] += __shfl_xor(sum[r], off);
  }
  float val = 0.f;
  if (valid && ((lane >> 4) == l)) {
    const int sr = lane & 15;
#pragma unroll
    for (int r = 0; r < R_; ++r) if (sr == r) val = sum[r];
  }
  u_exp[(size_t)g * LR_ + lane] = f2bf(val);
}

// ---------------- LoRA v = act . down_a ----------------
__global__ void k_lora_v(const unsigned short* __restrict__ act, const float* __restrict__ dna,
                         const int* __restrict__ lidx, const int* __restrict__ pad_off,
                         const int* __restrict__ cnt, unsigned short* __restrict__ v_exp) {
  const int lane = threadIdx.x & 63;
  const int wid  = threadIdx.x >> 6;
  const int g = blockIdx.x * 4 + wid;
  int e = -1;
#pragma unroll
  for (int i = 0; i < E_; ++i)
    if (g >= pad_off[i] && g < pad_off[i + 1]) e = i;
  const bool valid = (e >= 0) && ((g - pad_off[e]) < cnt[e]);
  float sum[R_];
#pragma unroll
  for (int r = 0; r < R_; ++r) sum[r] = 0.f;
  int l = 0;
  if (valid) {
    l = lidx[g];
    const unsigned short* av_p = act + (size_t)g * I_;
    const float* ap = dna + ((size_t)l * E_ + e) * R_ * I_;
    for (int k = lane; k < I_; k += 64) {
      const float av = bf2f(av_p[k]);
#pragma unroll
      for (int r = 0; r < R_; ++r) sum[r] += av * ap[(size_t)r * I_ + k];
    }
#pragma unroll
    for (int r = 0; r < R_; ++r)
#pragma unroll
      for (int off = 32; off > 0; off >>= 1) sum[r] += __shfl_xor(sum[r], off);
  }
  float val = 0.f;
  if (valid && ((lane >> 4) == l)) {
    const int sr = lane & 15;
#pragma unroll
    for (int r = 0; r < R_; ++r) if (sr == r) val = sum[r];
  }
  v_exp[(size_t)g * LR_ + lane] = f2bf(val);
}

// ---------------- phase 1: gate_up GEMM (+LoRA via K-extension) + SwiGLU ----------------
__global__ __launch_bounds__(256, 2)
void k_gemm1(const float* __restrict__ hidden, const float* __restrict__ w13,
             const float* __restrict__ gub, const unsigned short* __restrict__ u_exp,
             const int* __restrict__ tok, const int* __restrict__ pad_off,
             const int* __restrict__ cnt, unsigned short* __restrict__ act) {
  __shared__ __align__(16) unsigned short sA [BM * BK];
  __shared__ __align__(16) unsigned short sBg[BN * BK];
  __shared__ __align__(16) unsigned short sBu[BN * BK];

  const int base = blockIdx.y * BM;
  if (base >= pad_off[E_]) return;
  int e = 0;
#pragma unroll
  for (int i = 1; i < E_; ++i) if (base >= pad_off[i]) e = i;
  const int erow0 = pad_off[e];
  const int cnt_e = cnt[e];
  const int n0 = blockIdx.x * BN;

  const int tid  = threadIdx.x;
  const int lane = tid & 63;
  const int wid  = tid >> 6;
  const int wm   = (wid >> 1) * 64;
  const int wn   = (wid & 1) * 64;
  const int quad = lane >> 4;
  const int mr   = lane & 15;

  f32x4 zero = {0.f, 0.f, 0.f, 0.f};
  f32x4 accg[4][4], accu[4][4];
#pragma unroll
  for (int i = 0; i < 4; ++i)
#pragma unroll
    for (int j = 0; j < 4; ++j) { accg[i][j] = zero; accu[i][j] = zero; }

  for (int kt = 0; kt < KTOT1; kt += BK) {
    // stage A: 128 rows x 32 k (gathered token rows, fp32->bf16; LoRA strip is bf16)
#pragma unroll
    for (int it = 0; it < 4; ++it) {
      const int idx = tid + it * 256;
      const int row = idx >> 3, c4 = idx & 7;
      const int k = kt + c4 * 4;
      if (k < H_) {
        const int t = ((base - erow0 + row) < cnt_e) ? tok[base + row] : 0;
        const float4 f = *(const float4*)(hidden + (size_t)t * H_ + k);
        *(uint2*)&sA[row * BK + c4 * 4] = make_uint2(pack2(f.x, f.y), pack2(f.z, f.w));
      } else {
        const unsigned short* up = u_exp + (size_t)(base + row) * LR_ + (k - H_);
        *(uint2*)&sA[row * BK + c4 * 4] = *(const uint2*)up;
      }
    }
    // stage B (gate and up halves of w13; LoRA region from gu_lora_b)
#pragma unroll
    for (int it = 0; it < 4; ++it) {
      const int idx = tid + it * 256;
      const int row = idx >> 3, c4 = idx & 7;
      const int k = kt + c4 * 4;
      const int ng = n0 + row;
      float4 fg, fu;
      if (k < H_) {
        fg = *(const float4*)(w13 + ((size_t)e * I2_ + ng) * H_ + k);
        fu = *(const float4*)(w13 + ((size_t)e * I2_ + I_ + ng) * H_ + k);
      } else {
        const int kk = k - H_;
        const int l = kk >> 4, r = kk & 15;
        fg = *(const float4*)(gub + (((size_t)l * E_ + e) * I2_ + ng) * R_ + r);
        fu = *(const float4*)(gub + (((size_t)l * E_ + e) * I2_ + I_ + ng) * R_ + r);
      }
      *(uint2*)&sBg[row * BK + c4 * 4] = make_uint2(pack2(fg.x, fg.y), pack2(fg.z, fg.w));
      *(uint2*)&sBu[row * BK + c4 * 4] = make_uint2(pack2(fu.x, fu.y), pack2(fu.z, fu.w));
    }
    __syncthreads();

    bf16x8 af[4], bg[4], bu[4];
#pragma unroll
    for (int i = 0; i < 4; ++i)
      af[i] = *(const bf16x8*)&sA[(wm + i * 16 + mr) * BK + quad * 8];
#pragma unroll
    for (int j = 0; j < 4; ++j) {
      bg[j] = *(const bf16x8*)&sBg[(wn + j * 16 + mr) * BK + quad * 8];
      bu[j] = *(const bf16x8*)&sBu[(wn + j * 16 + mr) * BK + quad * 8];
    }
#pragma unroll
    for (int i = 0; i < 4; ++i)
#pragma unroll
      for (int j = 0; j < 4; ++j) {
        accg[i][j] = __builtin_amdgcn_mfma_f32_16x16x32_bf16(af[i], bg[j], accg[i][j], 0, 0, 0);
        accu[i][j] = __builtin_amdgcn_mfma_f32_16x16x32_bf16(af[i], bu[j], accu[i][j], 0, 0, 0);
      }
    __syncthreads();
  }

  // epilogue: SwiGLU -> act (bf16). C/D layout: row = quad*4+reg, col = lane&15.
#pragma unroll
  for (int i = 0; i < 4; ++i)
#pragma unroll
    for (int j = 0; j < 4; ++j)
#pragma unroll
      for (int r = 0; r < 4; ++r) {
        const int m = wm + i * 16 + quad * 4 + r;
        const int n = wn + j * 16 + mr;
        const float gv = accg[i][j][r];
        const float uv = accu[i][j][r];
        const float s = gv / (1.f + __expf(-gv));
        act[(size_t)(base + m) * I_ + (n0 + n)] = f2bf(s * uv);
      }
}

// ---------------- phase 2: down GEMM (+LoRA via K-extension) + weighted atomic combine ----------------
__global__ __launch_bounds__(256, 2)
void k_gemm2(const unsigned short* __restrict__ act, const float* __restrict__ w2,
             const float* __restrict__ dnb, const unsigned short* __restrict__ v_exp,
             const int* __restrict__ tok, const float* __restrict__ wgt,
             const int* __restrict__ pad_off, const int* __restrict__ cnt,
             float* __restrict__ out) {
  __shared__ __align__(16) unsigned short sA[BM * BK];
  __shared__ __align__(16) unsigned short sB[BN * BK];

  const int base = blockIdx.y * BM;
  if (base >= pad_off[E_]) return;
  int e = 0;
#pragma unroll
  for (int i = 1; i < E_; ++i) if (base >= pad_off[i]) e = i;
  const int erow0 = pad_off[e];
  const int cnt_e = cnt[e];
  const int n0 = blockIdx.x * BN;

  const int tid  = threadIdx.x;
  const int lane = tid & 63;
  const int wid  = tid >> 6;
  const int wm   = (wid >> 1) * 64;
  const int wn   = (wid & 1) * 64;
  const int quad = lane >> 4;
  const int mr   = lane & 15;

  f32x4 zero = {0.f, 0.f, 0.f, 0.f};
  f32x4 acc[4][4];
#pragma unroll
  for (int i = 0; i < 4; ++i)
#pragma unroll
    for (int j = 0; j < 4; ++j) acc[i][j] = zero;

  for (int kt = 0; kt < KTOT2; kt += BK) {
    // stage A: bf16 act rows (or v_exp LoRA strip), 16B copies
#pragma unroll
    for (int it = 0; it < 2; ++it) {
      const int idx = tid + it * 256;
      const int row = idx >> 2, c8 = idx & 3;
      const int k = kt + c8 * 8;
      const unsigned short* src = (k < I_)
          ? (act + (size_t)(base + row) * I_ + k)
          : (v_exp + (size_t)(base + row) * LR_ + (k - I_));
      *(uint4*)&sA[row * BK + c8 * 8] = *(const uint4*)src;
    }
    // stage B: w2 (fp32->bf16), LoRA region from down_lora_b
#pragma unroll
    for (int it = 0; it < 4; ++it) {
      const int idx = tid + it * 256;
      const int row = idx >> 3, c4 = idx & 7;
      const int k = kt + c4 * 4;
      const int ng = n0 + row;
      float4 f;
      if (k < I_) {
        f = *(const float4*)(w2 + ((size_t)e * H_ + ng) * I_ + k);
      } else {
        const int kk = k - I_;
        const int l = kk >> 4, r = kk & 15;
        f = *(const float4*)(dnb + (((size_t)l * E_ + e) * H_ + ng) * R_ + r);
      }
      *(uint2*)&sB[row * BK + c4 * 4] = make_uint2(pack2(f.x, f.y), pack2(f.z, f.w));
    }
    __syncthreads();

    bf16x8 af[4], bb[4];
#pragma unroll
    for (int i = 0; i < 4; ++i)
      af[i] = *(const bf16x8*)&sA[(wm + i * 16 + mr) * BK + quad * 8];
#pragma unroll
    for (int j = 0; j < 4; ++j)
      bb[j] = *(const bf16x8*)&sB[(wn + j * 16 + mr) * BK + quad * 8];
#pragma unroll
    for (int i = 0; i < 4; ++i)
#pragma unroll
      for (int j = 0; j < 4; ++j)
        acc[i][j] = __builtin_amdgcn_mfma_f32_16x16x32_bf16(af[i], bb[j], acc[i][j], 0, 0, 0);
    __syncthreads();
  }

  // epilogue: out[t, n] += w * d   (<=2 slots per token -> atomics)
#pragma unroll
  for (int i = 0; i < 4; ++i)
#pragma unroll
    for (int j = 0; j < 4; ++j)
#pragma unroll
      for (int r = 0; r < 4; ++r) {
        const int m = wm + i * 16 + quad * 4 + r;
        const int g = base + m;
        if ((g - erow0) < cnt_e) {
          const int n = wn + j * 16 + mr;
          atomicAdd(&out[(size_t)tok[g] * H_ + (n0 + n)], wgt[g] * acc[i][j][r]);
        }
      }
}

extern "C" void kernel_launch(void* const* d_in, const int* in_sizes, int n_in,
                              void* d_out, int out_size, void* d_ws, size_t ws_size,
                              hipStream_t stream) {
  const float* hidden  = (const float*)d_in[0];
  const float* topk_w  = (const float*)d_in[1];
  const float* w13     = (const float*)d_in[2];
  const float* w2      = (const float*)d_in[3];
  const float* gua     = (const float*)d_in[4];
  const float* gub     = (const float*)d_in[5];
  const float* dna     = (const float*)d_in[6];
  const float* dnb     = (const float*)d_in[7];
  const int*   topk_id = (const int*)d_in[8];
  const int*   tli     = (const int*)d_in[9];
  float* out = (float*)d_out;

  char* ws = (char*)d_ws;
  int*   cnt     = (int*)(ws + 0);
  int*   cnt2    = (int*)(ws + 32);
  int*   pad_off = (int*)(ws + 64);
  int*   tok     = (int*)(ws + 256);
  float* wgt     = (float*)(ws + 256 + 4 * MAXPAD);
  int*   lidx    = (int*)(ws + 256 + 8 * MAXPAD);
  unsigned short* u_exp = (unsigned short*)(ws + 256 + 12 * MAXPAD);
  unsigned short* v_exp = (unsigned short*)(ws + 256 + 12 * MAXPAD + 2 * MAXPAD * LR_);
  unsigned short* act   = (unsigned short*)(ws + 256 + 12 * MAXPAD + 4 * MAXPAD * LR_);
  // total ws use: 256 + 110592 + 2*1179648/2... = ~21.3 MB

  hipMemsetAsync(d_ws, 0, 256, stream);                       // counters
  hipMemsetAsync(d_out, 0, (size_t)T_ * H_ * sizeof(float), stream);

  k_count  <<<dim3((T_ * K_ + 255) / 256), dim3(256), 0, stream>>>(topk_id, cnt);
  k_prefix <<<dim3(1), dim3(64), 0, stream>>>(cnt, pad_off);
  k_scatter<<<dim3((T_ * K_ + 255) / 256), dim3(256), 0, stream>>>(topk_id, topk_w, tli, pad_off,
                                                                   cnt2, tok, wgt, lidx);
  k_lora_u <<<dim3(MAXPAD / 4), dim3(256), 0, stream>>>(hidden, gua, tok, lidx, pad_off, cnt, u_exp);
  k_gemm1  <<<dim3(I_ / BN, MAXPAD / BM), dim3(256), 0, stream>>>(hidden, w13, gub, u_exp, tok,
                                                                  pad_off, cnt, act);
  k_lora_v <<<dim3(MAXPAD / 4), dim3(256), 0, stream>>>(act, dna, lidx, pad_off, cnt, v_exp);
  k_gemm2  <<<dim3(H_ / BN, MAXPAD / BM), dim3(256), 0, stream>>>(act, w2, dnb, v_exp, tok, wgt,
                                                                  pad_off, cnt, out);
}

// Round 2
// 808.338 us; speedup vs baseline: 1.3845x; 1.3845x over previous
//
#include <hip/hip_runtime.h>
#include <hip/hip_bf16.h>

// FusedMoEWithLoRA: grouped bf16-MFMA GEMMs, m97-style global_load_lds staging.
// Pre-pass converts weights+activations to bf16 with LoRA B-matrices folded
// into the GEMM K dimension (K += L*R = 64); per-token adapter masking is
// applied to the expanded u/v strips.

#define E_   8
#define H_   2048
#define I_   1024
#define I2_  2048
#define K_   2
#define L_   4
#define R_   16
#define T_   4096
#define LR_  64
#define BM   128
#define BN   128
#define BK   32
#define MAXPAD 9216
#define KTOT1 (H_ + LR_)   // 2112
#define KTOT2 (I_ + LR_)   // 1088

typedef __attribute__((ext_vector_type(8))) __bf16 bf16x8;
typedef __attribute__((ext_vector_type(4))) float  f32x4;

__device__ __forceinline__ unsigned short f2bf(float f) {
  union { float f; unsigned u; } v; v.f = f;
  unsigned u = v.u;
  u += 0x7fffu + ((u >> 16) & 1u);
  return (unsigned short)(u >> 16);
}
__device__ __forceinline__ unsigned pack2(float a, float b) {
  __hip_bfloat162 h = __float22bfloat162_rn(float2{a, b});
  union { __hip_bfloat162 h; unsigned u; } v; v.h = h;
  return v.u;
}
__device__ __forceinline__ float bf2f(unsigned short s) {
  union { unsigned u; float f; } v; v.u = ((unsigned)s) << 16;
  return v.f;
}
__device__ __forceinline__ void async16(const void* g, void* l) {
  __builtin_amdgcn_global_load_lds((const __attribute__((address_space(1))) void*)g,
                                   (__attribute__((address_space(3))) void*)l, 16, 0, 0);
}

// ---------------- routing ----------------
__global__ void k_count(const int* __restrict__ topk_ids, int* __restrict__ cnt) {
  int i = blockIdx.x * blockDim.x + threadIdx.x;
  if (i < T_ * K_) atomicAdd(&cnt[topk_ids[i]], 1);
}

__global__ void k_prefix(const int* __restrict__ cnt, int* __restrict__ pad_off) {
  if (threadIdx.x == 0) {
    int off = 0;
    for (int e = 0; e < E_; ++e) {
      pad_off[e] = off;
      off += ((cnt[e] + BM - 1) / BM) * BM;
    }
    pad_off[E_] = off;
  }
}

__global__ void k_scatter(const int* __restrict__ topk_ids, const float* __restrict__ topk_w,
                          const int* __restrict__ tli, const int* __restrict__ pad_off,
                          int* __restrict__ cnt2, int* __restrict__ tok,
                          float* __restrict__ wgt, int* __restrict__ lidx) {
  int i = blockIdx.x * blockDim.x + threadIdx.x;
  if (i < T_ * K_) {
    int e = topk_ids[i];
    int pos = atomicAdd(&cnt2[e], 1);
    int g = pad_off[e] + pos;
    int t = i / K_;
    tok[g] = t;
    wgt[g] = topk_w[i];
    lidx[g] = tli[t];
  }
}

// ---------------- bf16 weight conversion with LoRA-B strip concat ----------------
__global__ void k_cvt13(const float* __restrict__ w13, const float* __restrict__ gub,
                        unsigned short* __restrict__ w13x) {
  const int gr = blockIdx.x;            // e*2I + n
  const int e = gr >> 11, n = gr & (I2_ - 1);
  const int tid = threadIdx.x;
  const float* src = w13 + (size_t)gr * H_;
  unsigned short* dst = w13x + (size_t)gr * KTOT1;
#pragma unroll
  for (int c = tid; c < H_ / 4; c += 256) {
    float4 f = *(const float4*)(src + c * 4);
    *(uint2*)(dst + c * 4) = make_uint2(pack2(f.x, f.y), pack2(f.z, f.w));
  }
  if (tid < LR_) {
    const int l = tid >> 4, r = tid & 15;
    dst[H_ + tid] = f2bf(gub[(((size_t)l * E_ + e) * I2_ + n) * R_ + r]);
  }
}

__global__ void k_cvt2(const float* __restrict__ w2, const float* __restrict__ dnb,
                       unsigned short* __restrict__ w2x) {
  const int gr = blockIdx.x;            // e*H + n
  const int e = gr >> 11, n = gr & (H_ - 1);
  const int tid = threadIdx.x;
  const float* src = w2 + (size_t)gr * I_;
  unsigned short* dst = w2x + (size_t)gr * KTOT2;
  {
    const int c = tid;                  // I_/4 = 256 chunks, one per thread
    float4 f = *(const float4*)(src + c * 4);
    *(uint2*)(dst + c * 4) = make_uint2(pack2(f.x, f.y), pack2(f.z, f.w));
  }
  if (tid < LR_) {
    const int l = tid >> 4, r = tid & 15;
    dst[I_ + tid] = f2bf(dnb[(((size_t)l * E_ + e) * H_ + n) * R_ + r]);
  }
}

// ---------------- gather hidden rows into routed order (bf16) ----------------
__global__ void k_gather(const float* __restrict__ hidden, const int* __restrict__ tok,
                         const int* __restrict__ pad_off, const int* __restrict__ cnt,
                         unsigned short* __restrict__ x_rt) {
  const int g = blockIdx.x;
  const int tid = threadIdx.x;
  int e = -1;
#pragma unroll
  for (int i = 0; i < E_; ++i)
    if (g >= pad_off[i] && g < pad_off[i + 1]) e = i;
  const bool valid = (e >= 0) && ((g - pad_off[e]) < cnt[e]);
  const int t = valid ? tok[g] : 0;
  const float* src = hidden + (size_t)t * H_;
  unsigned short* dst = x_rt + (size_t)g * KTOT1;
#pragma unroll
  for (int c = tid; c < H_ / 4; c += 256) {
    uint2 v = make_uint2(0u, 0u);
    if (valid) {
      float4 f = *(const float4*)(src + c * 4);
      v = make_uint2(pack2(f.x, f.y), pack2(f.z, f.w));
    }
    *(uint2*)(dst + c * 4) = v;
  }
}

// ---------------- LoRA u strip (into x_rt columns [H, H+64)) ----------------
__global__ void k_lora_u(const float* __restrict__ hidden, const float* __restrict__ gua,
                         const int* __restrict__ tok, const int* __restrict__ lidx,
                         const int* __restrict__ pad_off, const int* __restrict__ cnt,
                         unsigned short* __restrict__ x_rt) {
  const int lane = threadIdx.x & 63;
  const int wid  = threadIdx.x >> 6;
  const int g = blockIdx.x * 4 + wid;
  int e = -1;
#pragma unroll
  for (int i = 0; i < E_; ++i)
    if (g >= pad_off[i] && g < pad_off[i + 1]) e = i;
  const bool valid = (e >= 0) && ((g - pad_off[e]) < cnt[e]);
  float sum[R_];
#pragma unroll
  for (int r = 0; r < R_; ++r) sum[r] = 0.f;
  int l = 0;
  if (valid) {
    const int t = tok[g];
    l = lidx[g];
    const float* hp = hidden + (size_t)t * H_;
    const float* ap = gua + ((size_t)l * E_ + e) * R_ * H_;
#pragma unroll
    for (int it = 0; it < H_ / 256; ++it) {
      const int k = (lane + it * 64) * 4;
      const float4 hv = *(const float4*)(hp + k);
#pragma unroll
      for (int r = 0; r < R_; ++r) {
        const float4 av = *(const float4*)(ap + (size_t)r * H_ + k);
        sum[r] += hv.x * av.x + hv.y * av.y + hv.z * av.z + hv.w * av.w;
      }
    }
#pragma unroll
    for (int r = 0; r < R_; ++r)
#pragma unroll
      for (int off = 32; off > 0; off >>= 1) sum[r] += __shfl_xor(sum[r], off);
  }
  float val = 0.f;
  if (valid && ((lane >> 4) == l)) {
    const int sr = lane & 15;
#pragma unroll
    for (int r = 0; r < R_; ++r) if (sr == r) val = sum[r];
  }
  x_rt[(size_t)g * KTOT1 + H_ + lane] = f2bf(val);
}

// ---------------- LoRA v strip (into act columns [I, I+64)) ----------------
__global__ void k_lora_v(unsigned short* __restrict__ act, const float* __restrict__ dna,
                         const int* __restrict__ lidx, const int* __restrict__ pad_off,
                         const int* __restrict__ cnt) {
  const int lane = threadIdx.x & 63;
  const int wid  = threadIdx.x >> 6;
  const int g = blockIdx.x * 4 + wid;
  int e = -1;
#pragma unroll
  for (int i = 0; i < E_; ++i)
    if (g >= pad_off[i] && g < pad_off[i + 1]) e = i;
  const bool valid = (e >= 0) && ((g - pad_off[e]) < cnt[e]);
  float sum[R_];
#pragma unroll
  for (int r = 0; r < R_; ++r) sum[r] = 0.f;
  int l = 0;
  if (valid) {
    l = lidx[g];
    const unsigned short* av_p = act + (size_t)g * KTOT2;
    const float* ap = dna + ((size_t)l * E_ + e) * R_ * I_;
#pragma unroll
    for (int it = 0; it < I_ / 256; ++it) {
      const int k = (lane + it * 64) * 4;
      const ushort4 a4 = *(const ushort4*)(av_p + k);
      const float ax = bf2f(a4.x), ay = bf2f(a4.y), az = bf2f(a4.z), aw = bf2f(a4.w);
#pragma unroll
      for (int r = 0; r < R_; ++r) {
        const float4 av = *(const float4*)(ap + (size_t)r * I_ + k);
        sum[r] += ax * av.x + ay * av.y + az * av.z + aw * av.w;
      }
    }
#pragma unroll
    for (int r = 0; r < R_; ++r)
#pragma unroll
      for (int off = 32; off > 0; off >>= 1) sum[r] += __shfl_xor(sum[r], off);
  }
  float val = 0.f;
  if (valid && ((lane >> 4) == l)) {
    const int sr = lane & 15;
#pragma unroll
    for (int r = 0; r < R_; ++r) if (sr == r) val = sum[r];
  }
  act[(size_t)g * KTOT2 + I_ + lane] = f2bf(val);
}

// ---------------- phase 1: gate_up GEMM + SwiGLU ----------------
__global__ __launch_bounds__(256, 2)
void k_gemm1(const unsigned short* __restrict__ x_rt, const unsigned short* __restrict__ w13x,
             const int* __restrict__ pad_off, unsigned short* __restrict__ act) {
  __shared__ __align__(16) unsigned short sA [BM * BK];
  __shared__ __align__(16) unsigned short sBg[BN * BK];
  __shared__ __align__(16) unsigned short sBu[BN * BK];

  const int base = blockIdx.y * BM;
  if (base >= pad_off[E_]) return;
  int e = 0;
#pragma unroll
  for (int i = 1; i < E_; ++i) if (base >= pad_off[i]) e = i;
  const int n0 = blockIdx.x * BN;

  const int tid  = threadIdx.x;
  const int lane = tid & 63;
  const int wid  = tid >> 6;
  const int wm   = (wid >> 1) * 64;
  const int wn   = (wid & 1) * 64;
  const int quad = lane >> 4;
  const int mr   = lane & 15;

  // staging: chunk c = tid + pass*256; row = c>>2, 16B piece = c&3
  const int srow = tid >> 2, spc = (tid & 3) * 8;
  const unsigned short* aS0  = x_rt + (size_t)(base + srow) * KTOT1 + spc;
  const unsigned short* aS1  = aS0 + (size_t)64 * KTOT1;
  const unsigned short* bgS0 = w13x + ((size_t)e * I2_ + n0 + srow) * KTOT1 + spc;
  const unsigned short* bgS1 = bgS0 + (size_t)64 * KTOT1;
  const unsigned short* buS0 = bgS0 + (size_t)I_ * KTOT1;
  const unsigned short* buS1 = buS0 + (size_t)64 * KTOT1;
  unsigned short* aD  = sA  + wid * 512;
  unsigned short* bgD = sBg + wid * 512;
  unsigned short* buD = sBu + wid * 512;

  f32x4 zero = {0.f, 0.f, 0.f, 0.f};
  f32x4 accg[4][4], accu[4][4];
#pragma unroll
  for (int i = 0; i < 4; ++i)
#pragma unroll
    for (int j = 0; j < 4; ++j) { accg[i][j] = zero; accu[i][j] = zero; }

  for (int kt = 0; kt < KTOT1; kt += BK) {
    async16(aS0,  aD);        async16(aS1,  aD + 2048);
    async16(bgS0, bgD);       async16(bgS1, bgD + 2048);
    async16(buS0, buD);       async16(buS1, buD + 2048);
    aS0 += BK; aS1 += BK; bgS0 += BK; bgS1 += BK; buS0 += BK; buS1 += BK;
    __syncthreads();

    bf16x8 af[4], bg[4], bu[4];
#pragma unroll
    for (int i = 0; i < 4; ++i)
      af[i] = *(const bf16x8*)&sA[(wm + i * 16 + mr) * BK + quad * 8];
#pragma unroll
    for (int j = 0; j < 4; ++j) {
      bg[j] = *(const bf16x8*)&sBg[(wn + j * 16 + mr) * BK + quad * 8];
      bu[j] = *(const bf16x8*)&sBu[(wn + j * 16 + mr) * BK + quad * 8];
    }
#pragma unroll
    for (int i = 0; i < 4; ++i)
#pragma unroll
      for (int j = 0; j < 4; ++j) {
        accg[i][j] = __builtin_amdgcn_mfma_f32_16x16x32_bf16(af[i], bg[j], accg[i][j], 0, 0, 0);
        accu[i][j] = __builtin_amdgcn_mfma_f32_16x16x32_bf16(af[i], bu[j], accu[i][j], 0, 0, 0);
      }
    __syncthreads();
  }

  // epilogue: SwiGLU -> act (row stride KTOT2). C/D: row = quad*4+reg, col = lane&15.
#pragma unroll
  for (int i = 0; i < 4; ++i)
#pragma unroll
    for (int j = 0; j < 4; ++j)
#pragma unroll
      for (int r = 0; r < 4; ++r) {
        const int m = wm + i * 16 + quad * 4 + r;
        const int n = wn + j * 16 + mr;
        const float gv = accg[i][j][r];
        const float uv = accu[i][j][r];
        const float s = gv / (1.f + __expf(-gv));
        act[(size_t)(base + m) * KTOT2 + (n0 + n)] = f2bf(s * uv);
      }
}

// ---------------- phase 2: down GEMM + weighted atomic combine ----------------
__global__ __launch_bounds__(256, 2)
void k_gemm2(const unsigned short* __restrict__ act, const unsigned short* __restrict__ w2x,
             const int* __restrict__ tok, const float* __restrict__ wgt,
             const int* __restrict__ pad_off, const int* __restrict__ cnt,
             float* __restrict__ out) {
  __shared__ __align__(16) unsigned short sA[BM * BK];
  __shared__ __align__(16) unsigned short sB[BN * BK];

  const int base = blockIdx.y * BM;
  if (base >= pad_off[E_]) return;
  int e = 0;
#pragma unroll
  for (int i = 1; i < E_; ++i) if (base >= pad_off[i]) e = i;
  const int erow0 = pad_off[e];
  const int cnt_e = cnt[e];
  const int n0 = blockIdx.x * BN;

  const int tid  = threadIdx.x;
  const int lane = tid & 63;
  const int wid  = tid >> 6;
  const int wm   = (wid >> 1) * 64;
  const int wn   = (wid & 1) * 64;
  const int quad = lane >> 4;
  const int mr   = lane & 15;

  const int srow = tid >> 2, spc = (tid & 3) * 8;
  const unsigned short* aS0 = act + (size_t)(base + srow) * KTOT2 + spc;
  const unsigned short* aS1 = aS0 + (size_t)64 * KTOT2;
  const unsigned short* bS0 = w2x + ((size_t)e * H_ + n0 + srow) * KTOT2 + spc;
  const unsigned short* bS1 = bS0 + (size_t)64 * KTOT2;
  unsigned short* aD = sA + wid * 512;
  unsigned short* bD = sB + wid * 512;

  f32x4 zero = {0.f, 0.f, 0.f, 0.f};
  f32x4 acc[4][4];
#pragma unroll
  for (int i = 0; i < 4; ++i)
#pragma unroll
    for (int j = 0; j < 4; ++j) acc[i][j] = zero;

  for (int kt = 0; kt < KTOT2; kt += BK) {
    async16(aS0, aD);  async16(aS1, aD + 2048);
    async16(bS0, bD);  async16(bS1, bD + 2048);
    aS0 += BK; aS1 += BK; bS0 += BK; bS1 += BK;
    __syncthreads();

    bf16x8 af[4], bb[4];
#pragma unroll
    for (int i = 0; i < 4; ++i)
      af[i] = *(const bf16x8*)&sA[(wm + i * 16 + mr) * BK + quad * 8];
#pragma unroll
    for (int j = 0; j < 4; ++j)
      bb[j] = *(const bf16x8*)&sB[(wn + j * 16 + mr) * BK + quad * 8];
#pragma unroll
    for (int i = 0; i < 4; ++i)
#pragma unroll
      for (int j = 0; j < 4; ++j)
        acc[i][j] = __builtin_amdgcn_mfma_f32_16x16x32_bf16(af[i], bb[j], acc[i][j], 0, 0, 0);
    __syncthreads();
  }

#pragma unroll
  for (int i = 0; i < 4; ++i)
#pragma unroll
    for (int j = 0; j < 4; ++j)
#pragma unroll
      for (int r = 0; r < 4; ++r) {
        const int m = wm + i * 16 + quad * 4 + r;
        const int g = base + m;
        if ((g - erow0) < cnt_e) {
          const int n = wn + j * 16 + mr;
          atomicAdd(&out[(size_t)tok[g] * H_ + (n0 + n)], wgt[g] * acc[i][j][r]);
        }
      }
}

extern "C" void kernel_launch(void* const* d_in, const int* in_sizes, int n_in,
                              void* d_out, int out_size, void* d_ws, size_t ws_size,
                              hipStream_t stream) {
  const float* hidden  = (const float*)d_in[0];
  const float* topk_w  = (const float*)d_in[1];
  const float* w13     = (const float*)d_in[2];
  const float* w2      = (const float*)d_in[3];
  const float* gua     = (const float*)d_in[4];
  const float* gub     = (const float*)d_in[5];
  const float* dna     = (const float*)d_in[6];
  const float* dnb     = (const float*)d_in[7];
  const int*   topk_id = (const int*)d_in[8];
  const int*   tli     = (const int*)d_in[9];
  float* out = (float*)d_out;

  char* ws = (char*)d_ws;
  int*   cnt     = (int*)(ws + 0);
  int*   cnt2    = (int*)(ws + 32);
  int*   pad_off = (int*)(ws + 64);
  size_t off = 256;
  int*   tok  = (int*)(ws + off);   off += 4 * MAXPAD;              // 36 KB
  float* wgt  = (float*)(ws + off); off += 4 * MAXPAD;
  int*   lidx = (int*)(ws + off);   off += 4 * MAXPAD;
  unsigned short* x_rt = (unsigned short*)(ws + off); off += (size_t)2 * MAXPAD * KTOT1; // 38.9 MB
  unsigned short* act  = (unsigned short*)(ws + off); off += (size_t)2 * MAXPAD * KTOT2; // 20.1 MB
  unsigned short* w13x = (unsigned short*)(ws + off); off += (size_t)2 * E_ * I2_ * KTOT1; // 69.2 MB
  unsigned short* w2x  = (unsigned short*)(ws + off); off += (size_t)2 * E_ * H_ * KTOT2;  // 35.7 MB
  // total ~164 MB

  hipMemsetAsync(d_ws, 0, 256, stream);
  hipMemsetAsync(d_out, 0, (size_t)T_ * H_ * sizeof(float), stream);

  k_count  <<<dim3((T_ * K_ + 255) / 256), dim3(256), 0, stream>>>(topk_id, cnt);
  k_prefix <<<dim3(1), dim3(64), 0, stream>>>(cnt, pad_off);
  k_scatter<<<dim3((T_ * K_ + 255) / 256), dim3(256), 0, stream>>>(topk_id, topk_w, tli, pad_off,
                                                                   cnt2, tok, wgt, lidx);
  k_cvt13  <<<dim3(E_ * I2_), dim3(256), 0, stream>>>(w13, gub, w13x);
  k_cvt2   <<<dim3(E_ * H_), dim3(256), 0, stream>>>(w2, dnb, w2x);
  k_gather <<<dim3(MAXPAD), dim3(256), 0, stream>>>(hidden, tok, pad_off, cnt, x_rt);
  k_lora_u <<<dim3(MAXPAD / 4), dim3(256), 0, stream>>>(hidden, gua, tok, lidx, pad_off, cnt, x_rt);
  k_gemm1  <<<dim3(I_ / BN, MAXPAD / BM), dim3(256), 0, stream>>>(x_rt, w13x, pad_off, act);
  k_lora_v <<<dim3(MAXPAD / 4), dim3(256), 0, stream>>>(act, dna, lidx, pad_off, cnt);
  k_gemm2  <<<dim3(H_ / BN, MAXPAD / BM), dim3(256), 0, stream>>>(act, w2x, tok, wgt,
                                                                  pad_off, cnt, out);
}